// Round 3
// baseline (179.491 us; speedup 1.0000x reference)
//
#include <hip/hip_runtime.h>

// ---------- helpers ----------
__device__ __forceinline__ float readlane_f(float v, int l) {
    return __int_as_float(__builtin_amdgcn_readlane(__float_as_int(v), l));
}

// ---------- kernel 1: conv 9x9 VALID + bias + relu -> XT f32 [12800][64] ----------
// x: [64,1,28,28] f32 ; conv_w: [32,1,9,9] f32 ; conv_b: [32] f32
// Writes XT[k][b] (k = c*400+p) transposed (stride-64 scatter; 3.2MB buffer, L2 merges).
// Blocks 0..15 also zero the 4096-float S1 accumulator.
__global__ __launch_bounds__(256) void conv_kernel(
    const float* __restrict__ X, const float* __restrict__ CW, const float* __restrict__ CB,
    float* __restrict__ XT, float* __restrict__ S1acc)
{
    int blk = blockIdx.x;            // b*32 + c
    int b = blk >> 5, c = blk & 31;
    int t = threadIdx.x;
    if (blk < 16) S1acc[blk * 256 + t] = 0.0f;

    __shared__ float xs[784];
    const float* xb = X + b * 784;
    for (int i = t; i < 784; i += 256) xs[i] = xb[i];
    __syncthreads();

    float bias = CB[c];
    const float* wc = CW + c * 81;   // block-uniform -> scalar loads
    for (int p = t; p < 400; p += 256) {
        int py = p / 20, px = p - py * 20;
        float acc = bias;
        #pragma unroll
        for (int dy = 0; dy < 9; ++dy) {
            const float* xr = &xs[(py + dy) * 28 + px];
            #pragma unroll
            for (int dx = 0; dx < 9; ++dx)
                acc = fmaf(xr[dx], wc[dy * 9 + dx], acc);
        }
        XT[(size_t)(c * 400 + p) * 64 + b] = acc > 0.f ? acc : 0.f;
    }
}

// ---------- kernel 2: the big W1 stream ----------
// s1[b,j,m] += sum_k xf[b,k] * (sum_c W1[j,k,m,c])
// grid (100, 8): x = k-block (128 k each), y = j. 256 thr = 4 waves, 32 k/wave.
// One wave per k-row: lane loads float4 (16B) -> whole 1KB row; m = lane>>3.
__global__ __launch_bounds__(256) void primary_kernel(
    const float* __restrict__ W1, const float* __restrict__ XT, float* __restrict__ S1acc)
{
    int kb = blockIdx.x;
    int j  = blockIdx.y;
    int t = threadIdx.x;
    int wave = t >> 6, lane = t & 63;
    int k0 = kb * 128 + wave * 32;
    const float4* Wp = reinterpret_cast<const float4*>(W1 + (size_t)j * 3276800) + lane;

    float acc[8] = {0.f,0.f,0.f,0.f,0.f,0.f,0.f,0.f};
    for (int kk = 0; kk < 32; ++kk) {
        int k = k0 + kk;
        float4 w = Wp[(size_t)k * 64];
        float s = w.x + w.y + w.z + w.w;
        // reduce across the 8 lanes sharing this m (lane>>3 group)
        s += __shfl_xor(s, 1);
        s += __shfl_xor(s, 2);
        s += __shfl_xor(s, 4);
        float xv = XT[k * 64 + lane];   // lane = b, coalesced 256B
        #pragma unroll
        for (int m = 0; m < 8; ++m)
            acc[m] = fmaf(xv, readlane_f(s, m * 8), acc[m]);
    }

    __shared__ float red[4][64][9];     // +1 pad: conflict-free stride 9
    #pragma unroll
    for (int m = 0; m < 8; ++m) red[wave][lane][m] = acc[m];
    __syncthreads();
    for (int idx = t; idx < 512; idx += 256) {
        int bb = idx >> 3, m = idx & 7;
        float v = red[0][bb][m] + red[1][bb][m] + red[2][bb][m] + red[3][bb][m];
        atomicAdd(&S1acc[(bb * 8 + j) * 8 + m], v);
    }
}

// ---------- kernel 3: squash v1, u2 transform, 3-iter routing, output ----------
// one block per batch element b
__global__ __launch_bounds__(256) void routing_kernel(
    const float* __restrict__ W2, const float* __restrict__ S1acc,
    float* __restrict__ OUT)
{
    int b = blockIdx.x;
    int t = threadIdx.x;
    __shared__ float v1[64];        // [k=8][c=8]
    __shared__ float u2[10][8][16];
    __shared__ float blog[10][8];
    __shared__ float cw[10][8];
    __shared__ float sv[10][16];
    __shared__ float vv[10][16];
    __shared__ float fac[16];

    if (t < 64) v1[t] = S1acc[b * 64 + t] * 0.125f;   // softmax(0) over 8 caps = 1/8
    if (t >= 64 && t < 144) { int q = t - 64; blog[q >> 3][q & 7] = 0.f; }
    __syncthreads();
    if (t < 8) {   // squash per primary capsule: |s|/(1+|s|^2) * s
        float n2 = 0.f;
        #pragma unroll
        for (int m = 0; m < 8; ++m) { float x = v1[t * 8 + m]; n2 = fmaf(x, x, n2); }
        float n = sqrtf(n2);
        fac[t] = n / (1.f + n2);
    }
    __syncthreads();
    if (t < 64) v1[t] *= fac[t >> 3];
    __syncthreads();

    // u2[j][k][m] = sum_c W2[j,k,m,c] * v1[k][c]
    for (int idx = t; idx < 1280; idx += 256) {
        int j = idx >> 7;
        int r = idx & 127;
        int k = r >> 4, m = r & 15;
        const float* wp = W2 + idx * 8;   // [j][k][m][c] contiguous, idx == (j*8+k)*16+m
        float a = 0.f;
        #pragma unroll
        for (int c = 0; c < 8; ++c) a = fmaf(wp[c], v1[k * 8 + c], a);
        u2[j][k][m] = a;
    }
    __syncthreads();

    for (int it = 0; it < 3; ++it) {
        if (t < 8) {   // softmax over 10 classes for k = t
            float mx = -1e30f;
            #pragma unroll
            for (int j = 0; j < 10; ++j) mx = fmaxf(mx, blog[j][t]);
            float e[10], se = 0.f;
            #pragma unroll
            for (int j = 0; j < 10; ++j) { e[j] = expf(blog[j][t] - mx); se += e[j]; }
            float inv = 1.f / se;
            #pragma unroll
            for (int j = 0; j < 10; ++j) cw[j][t] = e[j] * inv;
        }
        __syncthreads();
        if (t < 160) {   // s[j][m] = sum_k c[j][k] * u2[j][k][m]
            int j = t >> 4, m = t & 15;
            float a = 0.f;
            #pragma unroll
            for (int k = 0; k < 8; ++k) a = fmaf(cw[j][k], u2[j][k][m], a);
            sv[j][m] = a;
        }
        __syncthreads();
        if (t < 10) {    // squash factor per class
            float n2 = 0.f;
            #pragma unroll
            for (int m = 0; m < 16; ++m) { float x = sv[t][m]; n2 = fmaf(x, x, n2); }
            float n = sqrtf(n2);
            fac[t] = n / (1.f + n2);
        }
        __syncthreads();
        if (t < 160) { int j = t >> 4, m = t & 15; vv[j][m] = sv[j][m] * fac[j]; }
        __syncthreads();
        if (it < 2) {
            if (t < 80) {   // b[j][k] += sum_m u2[j][k][m] * v[j][m]
                int j = t >> 3, k = t & 7;
                float d = 0.f;
                #pragma unroll
                for (int m = 0; m < 16; ++m) d = fmaf(u2[j][k][m], vv[j][m], d);
                blog[j][k] += d;
            }
            __syncthreads();
        }
    }
    if (t < 160) OUT[b * 160 + t] = vv[t >> 4][t & 15];
}

// ---------- launch ----------
extern "C" void kernel_launch(void* const* d_in, const int* in_sizes, int n_in,
                              void* d_out, int out_size, void* d_ws, size_t ws_size,
                              hipStream_t stream) {
    const float* X  = (const float*)d_in[0];
    const float* CW = (const float*)d_in[1];
    const float* CB = (const float*)d_in[2];
    const float* W1 = (const float*)d_in[3];
    const float* W2 = (const float*)d_in[4];
    float* S1 = (float*)d_ws;                         // 4096 f32 = 16 KB
    float* XT = (float*)((char*)d_ws + 16384);        // 819200 f32 = 3.2 MB
    float* OUT = (float*)d_out;

    conv_kernel<<<2048, 256, 0, stream>>>(X, CW, CB, XT, S1);
    primary_kernel<<<dim3(100, 8), 256, 0, stream>>>(W1, XT, S1);
    routing_kernel<<<64, 256, 0, stream>>>(W2, S1, OUT);
}

// Round 5
// 175.789 us; speedup vs baseline: 1.0211x; 1.0211x over previous
//
#include <hip/hip_runtime.h>

typedef float f4 __attribute__((ext_vector_type(4)));   // clang vector: NT-load legal

// ---------- helpers ----------
__device__ __forceinline__ float readlane_f(float v, int l) {
    return __int_as_float(__builtin_amdgcn_readlane(__float_as_int(v), l));
}

// ---------- kernel 1: conv 9x9 VALID + bias + relu -> XT f32 [12800][64] ----------
// x: [64,1,28,28] f32 ; conv_w: [32,1,9,9] f32 ; conv_b: [32] f32
// Writes XT[k][b] (k = c*400+p) transposed (stride-64 scatter; 3.2MB buffer, L2 merges).
// Blocks 0..15 also zero the 4096-float S1 accumulator.
__global__ __launch_bounds__(256) void conv_kernel(
    const float* __restrict__ X, const float* __restrict__ CW, const float* __restrict__ CB,
    float* __restrict__ XT, float* __restrict__ S1acc)
{
    int blk = blockIdx.x;            // b*32 + c
    int b = blk >> 5, c = blk & 31;
    int t = threadIdx.x;
    if (blk < 16) S1acc[blk * 256 + t] = 0.0f;

    __shared__ float xs[784];
    const f4* xb4 = reinterpret_cast<const f4*>(X + b * 784);
    if (t < 196) {                   // 196 float4 = 784 floats
        f4 v = xb4[t];
        float* d = &xs[t * 4];
        d[0] = v.x; d[1] = v.y; d[2] = v.z; d[3] = v.w;
    }
    __syncthreads();

    float bias = CB[c];
    const float* wc = CW + c * 81;   // block-uniform -> scalar loads
    for (int p = t; p < 400; p += 256) {
        int py = p / 20, px = p - py * 20;
        float acc = bias;
        #pragma unroll
        for (int dy = 0; dy < 9; ++dy) {
            const float* xr = &xs[(py + dy) * 28 + px];
            #pragma unroll
            for (int dx = 0; dx < 9; ++dx)
                acc = fmaf(xr[dx], wc[dy * 9 + dx], acc);
        }
        XT[(size_t)(c * 400 + p) * 64 + b] = acc > 0.f ? acc : 0.f;
    }
}

// ---------- kernel 2: the big W1 stream ----------
// s1[b,j,m] += sum_k xf[b,k] * (sum_c W1[j,k,m,c])
// grid (200, 8): x = k-block (64 k each), y = j. 256 thr = 4 waves, 16 k/wave.
// One wave per k-row: lane loads float4 (16B, non-temporal) -> whole 1KB row.
// 1600 blocks = 6.25/CU for latency hiding on the HBM stream.
__global__ __launch_bounds__(256) void primary_kernel(
    const float* __restrict__ W1, const float* __restrict__ XT, float* __restrict__ S1acc)
{
    int kb = blockIdx.x;
    int j  = blockIdx.y;
    int t = threadIdx.x;
    int wave = t >> 6, lane = t & 63;
    int k0 = kb * 64 + wave * 16;
    const f4* Wp = reinterpret_cast<const f4*>(W1) + (size_t)j * 819200
                   + (size_t)k0 * 64 + lane;
    const float* Xp = XT + (size_t)k0 * 64 + lane;

    float acc[8] = {0.f,0.f,0.f,0.f,0.f,0.f,0.f,0.f};
    #pragma unroll 4
    for (int kk = 0; kk < 16; ++kk) {
        f4 w = __builtin_nontemporal_load(Wp); Wp += 64;   // stream-once: bypass L2
        float xv = *Xp; Xp += 64;                          // L2-resident, coalesced
        float s = (w.x + w.y) + (w.z + w.w);
        // reduce across the 8 lanes sharing this m (lane>>3 group)
        s += __shfl_xor(s, 1);
        s += __shfl_xor(s, 2);
        s += __shfl_xor(s, 4);
        #pragma unroll
        for (int m = 0; m < 8; ++m)
            acc[m] = fmaf(xv, readlane_f(s, m * 8), acc[m]);
    }

    __shared__ float red[4][64][9];     // +1 pad: conflict-free stride 9
    #pragma unroll
    for (int m = 0; m < 8; ++m) red[wave][lane][m] = acc[m];
    __syncthreads();
    for (int idx = t; idx < 512; idx += 256) {
        int bb = idx >> 3, m = idx & 7;
        float v = red[0][bb][m] + red[1][bb][m] + red[2][bb][m] + red[3][bb][m];
        atomicAdd(&S1acc[(bb * 8 + j) * 8 + m], v);
    }
}

// ---------- kernel 3: squash v1, u2 transform, 3-iter routing, output ----------
// one block per batch element b
__global__ __launch_bounds__(256) void routing_kernel(
    const float* __restrict__ W2, const float* __restrict__ S1acc,
    float* __restrict__ OUT)
{
    int b = blockIdx.x;
    int t = threadIdx.x;
    __shared__ float v1[64];        // [k=8][c=8]
    __shared__ float u2[10][8][16];
    __shared__ float blog[10][8];
    __shared__ float cw[10][8];
    __shared__ float sv[10][16];
    __shared__ float vv[10][16];
    __shared__ float fac[16];

    if (t < 64) v1[t] = S1acc[b * 64 + t] * 0.125f;   // softmax(0) over 8 caps = 1/8
    if (t >= 64 && t < 144) { int q = t - 64; blog[q >> 3][q & 7] = 0.f; }
    __syncthreads();
    if (t < 8) {   // squash per primary capsule: |s|/(1+|s|^2) * s
        float n2 = 0.f;
        #pragma unroll
        for (int m = 0; m < 8; ++m) { float x = v1[t * 8 + m]; n2 = fmaf(x, x, n2); }
        float n = sqrtf(n2);
        fac[t] = n / (1.f + n2);
    }
    __syncthreads();
    if (t < 64) v1[t] *= fac[t >> 3];
    __syncthreads();

    // u2[j][k][m] = sum_c W2[j,k,m,c] * v1[k][c]
    for (int idx = t; idx < 1280; idx += 256) {
        int j = idx >> 7;
        int r = idx & 127;
        int k = r >> 4, m = r & 15;
        const float* wp = W2 + idx * 8;   // [j][k][m][c] contiguous, idx == (j*8+k)*16+m
        float a = 0.f;
        #pragma unroll
        for (int c = 0; c < 8; ++c) a = fmaf(wp[c], v1[k * 8 + c], a);
        u2[j][k][m] = a;
    }
    __syncthreads();

    for (int it = 0; it < 3; ++it) {
        if (t < 8) {   // softmax over 10 classes for k = t
            float mx = -1e30f;
            #pragma unroll
            for (int j = 0; j < 10; ++j) mx = fmaxf(mx, blog[j][t]);
            float e[10], se = 0.f;
            #pragma unroll
            for (int j = 0; j < 10; ++j) { e[j] = expf(blog[j][t] - mx); se += e[j]; }
            float inv = 1.f / se;
            #pragma unroll
            for (int j = 0; j < 10; ++j) cw[j][t] = e[j] * inv;
        }
        __syncthreads();
        if (t < 160) {   // s[j][m] = sum_k c[j][k] * u2[j][k][m]
            int j = t >> 4, m = t & 15;
            float a = 0.f;
            #pragma unroll
            for (int k = 0; k < 8; ++k) a = fmaf(cw[j][k], u2[j][k][m], a);
            sv[j][m] = a;
        }
        __syncthreads();
        if (t < 10) {    // squash factor per class
            float n2 = 0.f;
            #pragma unroll
            for (int m = 0; m < 16; ++m) { float x = sv[t][m]; n2 = fmaf(x, x, n2); }
            float n = sqrtf(n2);
            fac[t] = n / (1.f + n2);
        }
        __syncthreads();
        if (t < 160) { int j = t >> 4, m = t & 15; vv[j][m] = sv[j][m] * fac[j]; }
        __syncthreads();
        if (it < 2) {
            if (t < 80) {   // b[j][k] += sum_m u2[j][k][m] * v[j][m]
                int j = t >> 3, k = t & 7;
                float d = 0.f;
                #pragma unroll
                for (int m = 0; m < 16; ++m) d = fmaf(u2[j][k][m], vv[j][m], d);
                blog[j][k] += d;
            }
            __syncthreads();
        }
    }
    if (t < 160) OUT[b * 160 + t] = vv[t >> 4][t & 15];
}

// ---------- launch ----------
extern "C" void kernel_launch(void* const* d_in, const int* in_sizes, int n_in,
                              void* d_out, int out_size, void* d_ws, size_t ws_size,
                              hipStream_t stream) {
    const float* X  = (const float*)d_in[0];
    const float* CW = (const float*)d_in[1];
    const float* CB = (const float*)d_in[2];
    const float* W1 = (const float*)d_in[3];
    const float* W2 = (const float*)d_in[4];
    float* S1 = (float*)d_ws;                         // 4096 f32 = 16 KB
    float* XT = (float*)((char*)d_ws + 16384);        // 819200 f32 = 3.2 MB
    float* OUT = (float*)d_out;

    conv_kernel<<<2048, 256, 0, stream>>>(X, CW, CB, XT, S1);
    primary_kernel<<<dim3(200, 8), 256, 0, stream>>>(W1, XT, S1);
    routing_kernel<<<64, 256, 0, stream>>>(W2, S1, OUT);
}

// Round 6
// 174.759 us; speedup vs baseline: 1.0271x; 1.0059x over previous
//
#include <hip/hip_runtime.h>

typedef float f4 __attribute__((ext_vector_type(4)));   // clang vector: NT-load legal

// ---------- helpers ----------
__device__ __forceinline__ float readlane_f(float v, int l) {
    return __int_as_float(__builtin_amdgcn_readlane(__float_as_int(v), l));
}

// ---------- kernel 1: conv 9x9 VALID + bias + relu -> XT f32 [12800][64] ----------
// x: [64,1,28,28] f32 ; conv_w: [32,1,9,9] f32 ; conv_b: [32] f32
// Writes XT[k][b] (k = c*400+p) transposed (stride-64 scatter; 3.2MB buffer, L2 merges).
// Weights are block-uniform -> SGPR-resident (hoisted). Image in LDS, conflict-free
// (lane-adjacent p -> bank-distinct addresses; SQ_LDS_BANK_CONFLICT measured 0).
// Blocks 0..15 also zero the 4096-float S1 accumulator.
__global__ __launch_bounds__(256) void conv_kernel(
    const float* __restrict__ X, const float* __restrict__ CW, const float* __restrict__ CB,
    float* __restrict__ XT, float* __restrict__ S1acc)
{
    int blk = blockIdx.x;            // b*32 + c
    int b = blk >> 5, c = blk & 31;
    int t = threadIdx.x;
    if (blk < 16) S1acc[blk * 256 + t] = 0.0f;

    __shared__ float xs[784];
    const f4* xb4 = reinterpret_cast<const f4*>(X + b * 784);
    if (t < 196) {                   // 196 float4 = 784 floats
        f4 v = xb4[t];
        float* d = &xs[t * 4];
        d[0] = v.x; d[1] = v.y; d[2] = v.z; d[3] = v.w;
    }
    __syncthreads();

    float bias = CB[c];
    const float* wcg = CW + c * 81;
    float w[81];                     // block-uniform -> compiler scalarizes to SGPRs
    #pragma unroll
    for (int i = 0; i < 81; ++i) w[i] = wcg[i];

    for (int p = t; p < 400; p += 256) {
        int py = p / 20, px = p - py * 20;
        float acc = bias;
        #pragma unroll
        for (int dy = 0; dy < 9; ++dy) {
            const float* xr = &xs[(py + dy) * 28 + px];
            #pragma unroll
            for (int dx = 0; dx < 9; ++dx)
                acc = fmaf(xr[dx], w[dy * 9 + dx], acc);
        }
        XT[(size_t)(c * 400 + p) * 64 + b] = acc > 0.f ? acc : 0.f;
    }
}

// ---------- kernel 2: the big W1 stream ----------
// s1[b,j,m] += sum_k xf[b,k] * (sum_c W1[j,k,m,c])
// grid (200, 8): x = k-block (64 k each), y = j. 256 thr = 4 waves, 16 k/wave.
// One wave per k-row: lane loads float4 (16B, non-temporal) -> whole 1KB row.
// unroll 8: 8 NT loads in flight per wave; BW-bound (floor 15.4 us @ 6.8 TB/s).
__global__ __launch_bounds__(256) void primary_kernel(
    const float* __restrict__ W1, const float* __restrict__ XT, float* __restrict__ S1acc)
{
    int kb = blockIdx.x;
    int j  = blockIdx.y;
    int t = threadIdx.x;
    int wave = t >> 6, lane = t & 63;
    int k0 = kb * 64 + wave * 16;
    const f4* Wp = reinterpret_cast<const f4*>(W1) + (size_t)j * 819200
                   + (size_t)k0 * 64 + lane;
    const float* Xp = XT + (size_t)k0 * 64 + lane;

    float acc[8] = {0.f,0.f,0.f,0.f,0.f,0.f,0.f,0.f};
    #pragma unroll 8
    for (int kk = 0; kk < 16; ++kk) {
        f4 w = __builtin_nontemporal_load(Wp); Wp += 64;   // stream-once: bypass L2
        float xv = *Xp; Xp += 64;                          // L2-resident, coalesced
        float s = (w.x + w.y) + (w.z + w.w);
        // reduce across the 8 lanes sharing this m (lane>>3 group)
        s += __shfl_xor(s, 1);
        s += __shfl_xor(s, 2);
        s += __shfl_xor(s, 4);
        #pragma unroll
        for (int m = 0; m < 8; ++m)
            acc[m] = fmaf(xv, readlane_f(s, m * 8), acc[m]);
    }

    __shared__ float red[4][64][9];     // +1 pad: conflict-free stride 9
    #pragma unroll
    for (int m = 0; m < 8; ++m) red[wave][lane][m] = acc[m];
    __syncthreads();
    for (int idx = t; idx < 512; idx += 256) {
        int bb = idx >> 3, m = idx & 7;
        float v = red[0][bb][m] + red[1][bb][m] + red[2][bb][m] + red[3][bb][m];
        atomicAdd(&S1acc[(bb * 8 + j) * 8 + m], v);
    }
}

// ---------- kernel 3: squash v1, u2 transform, 3-iter routing, output ----------
// one block per batch element b
__global__ __launch_bounds__(256) void routing_kernel(
    const float* __restrict__ W2, const float* __restrict__ S1acc,
    float* __restrict__ OUT)
{
    int b = blockIdx.x;
    int t = threadIdx.x;
    __shared__ float v1[64];        // [k=8][c=8]
    __shared__ float u2[10][8][16];
    __shared__ float blog[10][8];
    __shared__ float cw[10][8];
    __shared__ float sv[10][16];
    __shared__ float vv[10][16];
    __shared__ float fac[16];

    if (t < 64) v1[t] = S1acc[b * 64 + t] * 0.125f;   // softmax(0) over 8 caps = 1/8
    if (t >= 64 && t < 144) { int q = t - 64; blog[q >> 3][q & 7] = 0.f; }
    __syncthreads();
    if (t < 8) {   // squash per primary capsule: |s|/(1+|s|^2) * s
        float n2 = 0.f;
        #pragma unroll
        for (int m = 0; m < 8; ++m) { float x = v1[t * 8 + m]; n2 = fmaf(x, x, n2); }
        float n = sqrtf(n2);
        fac[t] = n / (1.f + n2);
    }
    __syncthreads();
    if (t < 64) v1[t] *= fac[t >> 3];
    __syncthreads();

    // u2[j][k][m] = sum_c W2[j,k,m,c] * v1[k][c]
    for (int idx = t; idx < 1280; idx += 256) {
        int j = idx >> 7;
        int r = idx & 127;
        int k = r >> 4, m = r & 15;
        const float* wp = W2 + idx * 8;   // [j][k][m][c] contiguous, idx == (j*8+k)*16+m
        float a = 0.f;
        #pragma unroll
        for (int c = 0; c < 8; ++c) a = fmaf(wp[c], v1[k * 8 + c], a);
        u2[j][k][m] = a;
    }
    __syncthreads();

    for (int it = 0; it < 3; ++it) {
        if (t < 8) {   // softmax over 10 classes for k = t
            float mx = -1e30f;
            #pragma unroll
            for (int j = 0; j < 10; ++j) mx = fmaxf(mx, blog[j][t]);
            float e[10], se = 0.f;
            #pragma unroll
            for (int j = 0; j < 10; ++j) { e[j] = expf(blog[j][t] - mx); se += e[j]; }
            float inv = 1.f / se;
            #pragma unroll
            for (int j = 0; j < 10; ++j) cw[j][t] = e[j] * inv;
        }
        __syncthreads();
        if (t < 160) {   // s[j][m] = sum_k c[j][k] * u2[j][k][m]
            int j = t >> 4, m = t & 15;
            float a = 0.f;
            #pragma unroll
            for (int k = 0; k < 8; ++k) a = fmaf(cw[j][k], u2[j][k][m], a);
            sv[j][m] = a;
        }
        __syncthreads();
        if (t < 10) {    // squash factor per class
            float n2 = 0.f;
            #pragma unroll
            for (int m = 0; m < 16; ++m) { float x = sv[t][m]; n2 = fmaf(x, x, n2); }
            float n = sqrtf(n2);
            fac[t] = n / (1.f + n2);
        }
        __syncthreads();
        if (t < 160) { int j = t >> 4, m = t & 15; vv[j][m] = sv[j][m] * fac[j]; }
        __syncthreads();
        if (it < 2) {
            if (t < 80) {   // b[j][k] += sum_m u2[j][k][m] * v[j][m]
                int j = t >> 3, k = t & 7;
                float d = 0.f;
                #pragma unroll
                for (int m = 0; m < 16; ++m) d = fmaf(u2[j][k][m], vv[j][m], d);
                blog[j][k] += d;
            }
            __syncthreads();
        }
    }
    if (t < 160) OUT[b * 160 + t] = vv[t >> 4][t & 15];
}

// ---------- launch ----------
extern "C" void kernel_launch(void* const* d_in, const int* in_sizes, int n_in,
                              void* d_out, int out_size, void* d_ws, size_t ws_size,
                              hipStream_t stream) {
    const float* X  = (const float*)d_in[0];
    const float* CW = (const float*)d_in[1];
    const float* CB = (const float*)d_in[2];
    const float* W1 = (const float*)d_in[3];
    const float* W2 = (const float*)d_in[4];
    float* S1 = (float*)d_ws;                         // 4096 f32 = 16 KB
    float* XT = (float*)((char*)d_ws + 16384);        // 819200 f32 = 3.2 MB
    float* OUT = (float*)d_out;

    conv_kernel<<<2048, 256, 0, stream>>>(X, CW, CB, XT, S1);
    primary_kernel<<<dim3(200, 8), 256, 0, stream>>>(W1, XT, S1);
    routing_kernel<<<64, 256, 0, stream>>>(W2, S1, OUT);
}